// Round 5
// baseline (1385.427 us; speedup 1.0000x reference)
//
#include <hip/hip_runtime.h>
#include <math.h>

#define N_NODES 100000
#define N_EDGES 1250000
#define IN_DIM 6
#define HID 64

#define BIN_SHIFT 10
#define BIN_NODES 1024
#define NBIN 98                    // ceil(100000/1024)
#define A_BLOCKS 250
#define EPB (N_EDGES / A_BLOCKS)   // 5000 exactly
#define NSUB 8
#define SUB_NODES 128              // 1024/8
#define ASCAN_M (NBIN * A_BLOCKS)  // 24500

// --- phase A0: per-block bin histogram -> bbc[bin][block] ------------------
__global__ __launch_bounds__(256) void binA0(const int* __restrict__ dst, int* __restrict__ bbc) {
    __shared__ int cnt[NBIN];
    int t = threadIdx.x;
    if (t < NBIN) cnt[t] = 0;
    __syncthreads();
    int base = blockIdx.x * EPB;
    for (int i = t; i < EPB; i += 256)
        atomicAdd(&cnt[dst[base + i] >> BIN_SHIFT], 1);
    __syncthreads();
    if (t < NBIN) bbc[t * A_BLOCKS + blockIdx.x] = cnt[t];
}

// --- scan of bbc (bin-major) -> exact per-(block,bin) offsets + binstart ---
__global__ __launch_bounds__(256) void binScan(const int* __restrict__ bbc, int* __restrict__ bbs,
                                               int* __restrict__ binstart) {
    __shared__ int s[256];
    int t = threadIdx.x;
    const int chunk = (ASCAN_M + 255) / 256;  // 96
    int lo = t * chunk, hi = min(lo + chunk, ASCAN_M);
    int sum = 0;
    for (int i = lo; i < hi; ++i) sum += bbc[i];
    s[t] = sum;
    __syncthreads();
    for (int off = 1; off < 256; off <<= 1) {
        int add = (t >= off) ? s[t - off] : 0;
        __syncthreads();
        s[t] += add;
        __syncthreads();
    }
    int run = (t == 0) ? 0 : s[t - 1];
    for (int i = lo; i < hi; ++i) { bbs[i] = run; run += bbc[i]; }
    __syncthreads();
    for (int b = t; b < NBIN; b += 256) binstart[b] = bbs[b * A_BLOCKS];
    if (t == 0) binstart[NBIN] = N_EDGES;
}

// --- phase A1: write records into block-private regions (no global atomics)
__global__ __launch_bounds__(256) void binA1(const int* __restrict__ src, const int* __restrict__ dst,
                                             const int* __restrict__ bbs, unsigned* __restrict__ rec) {
    __shared__ int cur[NBIN];
    int t = threadIdx.x;
    if (t < NBIN) cur[t] = bbs[t * A_BLOCKS + blockIdx.x];
    __syncthreads();
    int base = blockIdx.x * EPB;
    for (int i = t; i < EPB; i += 256) {
        int d = dst[base + i];
        int s = src[base + i];
        int bin = d >> BIN_SHIFT;
        int pos = atomicAdd(&cur[bin], 1);
        rec[pos] = ((unsigned)(d & (BIN_NODES - 1)) << 17) | (unsigned)s;
    }
}

// --- dis from binned records: per-bin LDS node histogram -------------------
__global__ __launch_bounds__(256) void disK(const unsigned* __restrict__ rec,
                                            const int* __restrict__ binstart,
                                            float* __restrict__ dis) {
    __shared__ int h[BIN_NODES];
    int t = threadIdx.x;
    for (int i = t; i < BIN_NODES; i += 256) h[i] = 0;
    __syncthreads();
    int beg = binstart[blockIdx.x], end = binstart[blockIdx.x + 1];
    for (int j = beg + t; j < end; j += 256) atomicAdd(&h[rec[j] >> 17], 1);
    __syncthreads();
    int nb = blockIdx.x << BIN_SHIFT;
    for (int i = t; i < BIN_NODES; i += 256) {
        int n = nb + i;
        if (n < N_NODES) dis[n] = rsqrtf((float)h[i] + 1.0f);
    }
}

// --- p1 = (x @ W1) * dis[n]  (6 -> 64) -------------------------------------
__global__ void gemm1_kernel(const float* __restrict__ x, const float* __restrict__ W1,
                             const float* __restrict__ dis, float* __restrict__ p1) {
    __shared__ float w[IN_DIM * HID];
    int tid = threadIdx.x;
    for (int i = tid; i < IN_DIM * HID; i += blockDim.x) w[i] = W1[i];
    __syncthreads();
    int g = blockIdx.x * blockDim.x + tid;
    int n = g >> 6, c = g & 63;
    if (n >= N_NODES) return;
    float sum = 0.f;
#pragma unroll
    for (int k = 0; k < IN_DIM; ++k) sum += x[n * IN_DIM + k] * w[k * HID + c];
    p1[n * HID + c] = sum * dis[n];
}

// --- aggregation via LDS accumulator over one (bin, 1/8-sub-range) ---------
// out[n] = act(dis[n]*(acc[n] + p[n]) + b); READOUT fuses column-sum -> gsum
template <bool RELU, bool READOUT>
__global__ __launch_bounds__(512) void aggK(const float* __restrict__ p, const unsigned* __restrict__ rec,
                                            const int* __restrict__ binstart, const float* __restrict__ dis,
                                            const float* __restrict__ b, float* __restrict__ out,
                                            float* __restrict__ gsum) {
    __shared__ float acc[SUB_NODES * HID];   // 32 KB
    __shared__ float red[512];
    int t = threadIdx.x;
#pragma unroll
    for (int k = 0; k < 4; ++k) ((float4*)acc)[t + k * 512] = make_float4(0.f, 0.f, 0.f, 0.f);
    __syncthreads();
    int bin = blockIdx.x >> 3, sub = blockIdx.x & 7;
    int beg = binstart[bin], end = binstart[bin + 1];
    int wave = t >> 6, lane = t & 63;
    for (int jw = beg + wave * 8; jw < end; jw += 64) {
#pragma unroll
        for (int k = 0; k < 8; ++k) {
            int j = jw + k;
            if (j < end) {
                unsigned r = rec[j];
                int dl = (int)(r >> 17);
                if ((dl >> 7) == sub) {          // wave-uniform branch
                    int s = (int)(r & 131071u);
                    float v = p[(size_t)s * HID + lane];
                    atomicAdd(&acc[(dl & (SUB_NODES - 1)) * HID + lane], v);
                }
            }
        }
    }
    __syncthreads();
    int nodeBase = (bin << BIN_SHIFT) + sub * SUB_NODES;
    float bc = b[t & 63];
    if (READOUT) {
        float part = 0.f;
        for (int i = t; i < SUB_NODES * HID; i += 512) {
            int n = nodeBase + (i >> 6);
            if (n < N_NODES)
                part += dis[n] * (acc[i] + p[(size_t)n * HID + (i & 63)]) + bc;
        }
        red[t] = part;
        __syncthreads();
        if (t < 64) {
            float tot = 0.f;
#pragma unroll
            for (int w = 0; w < 8; ++w) tot += red[t + w * 64];
            atomicAdd(&gsum[t], tot);
        }
    } else {
        for (int i = t; i < SUB_NODES * HID; i += 512) {
            int n = nodeBase + (i >> 6);
            if (n < N_NODES) {
                float v = dis[n] * (acc[i] + p[(size_t)n * HID + (i & 63)]) + bc;
                out[(size_t)n * HID + (i & 63)] = RELU ? fmaxf(v, 0.f) : v;
            }
        }
    }
}

// --- p2 = (out1 @ W2) * dis[n]  (64 -> 64), LDS-tiled block GEMM -----------
#define G2_NODES 64
__global__ __launch_bounds__(256) void gemm2_kernel(const float* __restrict__ h,
                                                    const float* __restrict__ W2,
                                                    const float* __restrict__ dis,
                                                    float* __restrict__ p2) {
    __shared__ float w[HID * HID];
    __shared__ float ht[G2_NODES][HID + 1];
    int tid = threadIdx.x;
    for (int i = tid * 4; i < HID * HID; i += 256 * 4)
        *(float4*)&w[i] = *(const float4*)&W2[i];
    int n0 = blockIdx.x * G2_NODES;
    for (int i = tid; i < G2_NODES * HID / 4; i += 256) {
        int r = (i * 4) >> 6;
        int cc = (i * 4) & 63;
        float4 v = make_float4(0.f, 0.f, 0.f, 0.f);
        if (n0 + r < N_NODES) v = *(const float4*)&h[(size_t)(n0 + r) * HID + cc];
        ht[r][cc] = v.x; ht[r][cc + 1] = v.y; ht[r][cc + 2] = v.z; ht[r][cc + 3] = v.w;
    }
    __syncthreads();
    int c4 = (tid & 15) * 4;
    int nb = (tid >> 4) * 4;
    float acc[4][4];
#pragma unroll
    for (int i = 0; i < 4; ++i)
#pragma unroll
        for (int j = 0; j < 4; ++j) acc[i][j] = 0.f;
#pragma unroll 8
    for (int k = 0; k < HID; ++k) {
        float4 wv = *(float4*)&w[k * HID + c4];
        float h0 = ht[nb + 0][k];
        float h1 = ht[nb + 1][k];
        float h2 = ht[nb + 2][k];
        float h3 = ht[nb + 3][k];
        acc[0][0] += h0 * wv.x; acc[0][1] += h0 * wv.y; acc[0][2] += h0 * wv.z; acc[0][3] += h0 * wv.w;
        acc[1][0] += h1 * wv.x; acc[1][1] += h1 * wv.y; acc[1][2] += h1 * wv.z; acc[1][3] += h1 * wv.w;
        acc[2][0] += h2 * wv.x; acc[2][1] += h2 * wv.y; acc[2][2] += h2 * wv.z; acc[2][3] += h2 * wv.w;
        acc[3][0] += h3 * wv.x; acc[3][1] += h3 * wv.y; acc[3][2] += h3 * wv.z; acc[3][3] += h3 * wv.w;
    }
#pragma unroll
    for (int i = 0; i < 4; ++i) {
        int n = n0 + nb + i;
        if (n < N_NODES) {
            float ds = dis[n];
            float4 o = make_float4(acc[i][0] * ds, acc[i][1] * ds, acc[i][2] * ds, acc[i][3] * ds);
            *(float4*)&p2[(size_t)n * HID + c4] = o;
        }
    }
}

// --- final: sigmoid(mean(h2) @ Wfc + bfc) ----------------------------------
__global__ void final_kernel(const float* __restrict__ gsum, const float* __restrict__ Wfc,
                             const float* __restrict__ bfc, float* __restrict__ out) {
    int t = threadIdx.x;
    float v = gsum[t] * (1.0f / N_NODES) * Wfc[t];
    for (int off = 32; off > 0; off >>= 1) v += __shfl_down(v, off, 64);
    if (t == 0) out[0] = 1.0f / (1.0f + expf(-(v + bfc[0])));
}

extern "C" void kernel_launch(void* const* d_in, const int* in_sizes, int n_in,
                              void* d_out, int out_size, void* d_ws, size_t ws_size,
                              hipStream_t stream) {
    const float* x   = (const float*)d_in[0];
    const int*   ei  = (const int*)d_in[1];   // (2, E) row-major int32
    const float* W1  = (const float*)d_in[2];
    const float* b1  = (const float*)d_in[3];
    const float* W2  = (const float*)d_in[4];
    const float* b2  = (const float*)d_in[5];
    const float* Wfc = (const float*)d_in[6];
    const float* bfc = (const float*)d_in[7];
    const int* src = ei;
    const int* dst = ei + N_EDGES;

    char* ws = (char*)d_ws;
    size_t off = 0;
    auto alloc = [&](size_t bytes) {
        char* p = ws + off;
        off += (bytes + 255) & ~(size_t)255;
        return p;
    };
    float*    bufA     = (float*)   alloc((size_t)N_NODES * HID * 4);  // p1, then p2
    float*    bufB     = (float*)   alloc((size_t)N_NODES * HID * 4);  // out1
    float*    dis      = (float*)   alloc((size_t)N_NODES * 4);
    unsigned* rec      = (unsigned*)alloc((size_t)N_EDGES * 4);
    int*      bbc      = (int*)     alloc((size_t)ASCAN_M * 4);
    int*      bbs      = (int*)     alloc((size_t)ASCAN_M * 4);
    int*      binstart = (int*)     alloc((size_t)(NBIN + 1) * 4);
    float*    gsum     = (float*)   alloc(64 * 4);

    hipMemsetAsync(gsum, 0, 64 * 4, stream);

    int nb = (N_NODES * HID + 255) / 256;
    int g2b = (N_NODES + G2_NODES - 1) / G2_NODES;

    binA0<<<A_BLOCKS, 256, 0, stream>>>(dst, bbc);
    binScan<<<1, 256, 0, stream>>>(bbc, bbs, binstart);
    binA1<<<A_BLOCKS, 256, 0, stream>>>(src, dst, bbs, rec);
    disK<<<NBIN, 256, 0, stream>>>(rec, binstart, dis);
    gemm1_kernel<<<nb, 256, 0, stream>>>(x, W1, dis, bufA);
    aggK<true, false><<<NBIN * NSUB, 512, 0, stream>>>(bufA, rec, binstart, dis, b1, bufB, nullptr);
    gemm2_kernel<<<g2b, 256, 0, stream>>>(bufB, W2, dis, bufA);
    aggK<false, true><<<NBIN * NSUB, 512, 0, stream>>>(bufA, rec, binstart, dis, b2, nullptr, gsum);
    final_kernel<<<1, 64, 0, stream>>>(gsum, Wfc, bfc, (float*)d_out);
}

// Round 6
// 347.979 us; speedup vs baseline: 3.9814x; 3.9814x over previous
//
#include <hip/hip_runtime.h>
#include <math.h>

#define N_NODES 100000
#define N_EDGES 1250000
#define IN_DIM 6
#define HID 64

#define BIN_SHIFT 10
#define BIN_NODES 1024
#define NBIN 98                    // ceil(100000/1024)
#define A_BLOCKS 250
#define EPB (N_EDGES / A_BLOCKS)   // 5000 exactly
#define ASCAN_M (NBIN * A_BLOCKS)  // 24500

// --- phase A0: per-block bin histogram -> bbc[bin][block] ------------------
__global__ __launch_bounds__(256) void binA0(const int* __restrict__ dst, int* __restrict__ bbc) {
    __shared__ int cnt[NBIN];
    int t = threadIdx.x;
    if (t < NBIN) cnt[t] = 0;
    __syncthreads();
    int base = blockIdx.x * EPB;
    for (int i = t; i < EPB; i += 256)
        atomicAdd(&cnt[dst[base + i] >> BIN_SHIFT], 1);
    __syncthreads();
    if (t < NBIN) bbc[t * A_BLOCKS + blockIdx.x] = cnt[t];
}

// --- scan of bbc (bin-major) -> per-(block,bin) offsets + binstart ---------
__global__ __launch_bounds__(1024) void binScan(const int* __restrict__ bbc, int* __restrict__ bbs,
                                                int* __restrict__ binstart) {
    __shared__ int s[1024];
    int t = threadIdx.x;
    const int chunk = (ASCAN_M + 1023) / 1024;  // 24
    int lo = t * chunk, hi = min(lo + chunk, ASCAN_M);
    int sum = 0;
    for (int i = lo; i < hi; ++i) sum += bbc[i];
    s[t] = sum;
    __syncthreads();
    for (int off = 1; off < 1024; off <<= 1) {
        int add = (t >= off) ? s[t - off] : 0;
        __syncthreads();
        s[t] += add;
        __syncthreads();
    }
    int run = (t == 0) ? 0 : s[t - 1];
    for (int i = lo; i < hi; ++i) { bbs[i] = run; run += bbc[i]; }
    __syncthreads();
    for (int b = t; b < NBIN; b += 1024) binstart[b] = bbs[b * A_BLOCKS];
    if (t == 0) binstart[NBIN] = N_EDGES;
}

// --- phase A1: records into block-private regions (LDS cursors only) -------
__global__ __launch_bounds__(256) void binA1(const int* __restrict__ src, const int* __restrict__ dst,
                                             const int* __restrict__ bbs, unsigned* __restrict__ rec) {
    __shared__ int cur[NBIN];
    int t = threadIdx.x;
    if (t < NBIN) cur[t] = bbs[t * A_BLOCKS + blockIdx.x];
    __syncthreads();
    int base = blockIdx.x * EPB;
    for (int i = t; i < EPB; i += 256) {
        int d = dst[base + i];
        int s = src[base + i];
        int bin = d >> BIN_SHIFT;
        int pos = atomicAdd(&cur[bin], 1);
        rec[pos] = ((unsigned)(d & (BIN_NODES - 1)) << 17) | (unsigned)s;
    }
}

// --- per-bin CSR-ify: node hist -> scan -> dst-sorted src, row_ptr, dis ----
__global__ __launch_bounds__(256) void binCSR(const unsigned* __restrict__ rec,
                                              const int* __restrict__ binstart,
                                              unsigned* __restrict__ srcsorted,
                                              int* __restrict__ row_ptr, float* __restrict__ dis) {
    __shared__ int hist[BIN_NODES];   // counts, then cursors
    __shared__ int sc[256];
    int t = threadIdx.x;
    int bin = blockIdx.x;
    for (int i = t; i < BIN_NODES; i += 256) hist[i] = 0;
    __syncthreads();
    int beg = binstart[bin], end = binstart[bin + 1];
    for (int j = beg + t; j < end; j += 256) atomicAdd(&hist[rec[j] >> 17], 1);
    __syncthreads();
    int b4 = t * 4;
    int c0 = hist[b4], c1 = hist[b4 + 1], c2 = hist[b4 + 2], c3 = hist[b4 + 3];
    int tsum = c0 + c1 + c2 + c3;
    sc[t] = tsum;
    __syncthreads();
    for (int off = 1; off < 256; off <<= 1) {
        int add = (t >= off) ? sc[t - off] : 0;
        __syncthreads();
        sc[t] += add;
        __syncthreads();
    }
    int o0 = sc[t] - tsum;            // exclusive offsets within bin
    int o1 = o0 + c0, o2 = o1 + c1, o3 = o2 + c2;
    int n0 = (bin << BIN_SHIFT) + b4;
    if (n0 + 0 < N_NODES) { row_ptr[n0 + 0] = beg + o0; dis[n0 + 0] = rsqrtf((float)c0 + 1.0f); }
    if (n0 + 1 < N_NODES) { row_ptr[n0 + 1] = beg + o1; dis[n0 + 1] = rsqrtf((float)c1 + 1.0f); }
    if (n0 + 2 < N_NODES) { row_ptr[n0 + 2] = beg + o2; dis[n0 + 2] = rsqrtf((float)c2 + 1.0f); }
    if (n0 + 3 < N_NODES) { row_ptr[n0 + 3] = beg + o3; dis[n0 + 3] = rsqrtf((float)c3 + 1.0f); }
    if (bin == NBIN - 1 && t == 0) row_ptr[N_NODES] = N_EDGES;
    __syncthreads();
    hist[b4] = o0; hist[b4 + 1] = o1; hist[b4 + 2] = o2; hist[b4 + 3] = o3;
    __syncthreads();
    for (int j = beg + t; j < end; j += 256) {
        unsigned r = rec[j];
        int pos = atomicAdd(&hist[r >> 17], 1);
        srcsorted[beg + pos] = r & 131071u;
    }
}

// --- p1 = (x @ W1) * dis[n]  (6 -> 64) -------------------------------------
__global__ void gemm1_kernel(const float* __restrict__ x, const float* __restrict__ W1,
                             const float* __restrict__ dis, float* __restrict__ p1) {
    __shared__ float w[IN_DIM * HID];
    int tid = threadIdx.x;
    for (int i = tid; i < IN_DIM * HID; i += blockDim.x) w[i] = W1[i];
    __syncthreads();
    int g = blockIdx.x * blockDim.x + tid;
    int n = g >> 6, c = g & 63;
    if (n >= N_NODES) return;
    float sum = 0.f;
#pragma unroll
    for (int k = 0; k < IN_DIM; ++k) sum += x[n * IN_DIM + k] * w[k * HID + c];
    p1[n * HID + c] = sum * dis[n];
}

// --- aggregation: out[n] = act(dis[n]*(p[n] + sum_in p[src]) + b) ----------
// One wave per node, lane = channel, x4 unrolled gather (proven R2-R4 form).
template <bool RELU>
__global__ void agg_kernel(const float* __restrict__ p, const int* __restrict__ row_ptr,
                           const unsigned* __restrict__ srcsorted, const float* __restrict__ dis,
                           const float* __restrict__ b, float* __restrict__ out) {
    int g = blockIdx.x * blockDim.x + threadIdx.x;
    int n = g >> 6, c = g & 63;
    if (n >= N_NODES) return;
    int beg = row_ptr[n], end = row_ptr[n + 1];
    float a0 = p[(size_t)n * HID + c], a1 = 0.f, a2 = 0.f, a3 = 0.f;
    int j = beg;
    for (; j + 4 <= end; j += 4) {
        unsigned s0 = srcsorted[j];
        unsigned s1 = srcsorted[j + 1];
        unsigned s2 = srcsorted[j + 2];
        unsigned s3 = srcsorted[j + 3];
        a0 += p[(size_t)s0 * HID + c];
        a1 += p[(size_t)s1 * HID + c];
        a2 += p[(size_t)s2 * HID + c];
        a3 += p[(size_t)s3 * HID + c];
    }
    for (; j < end; ++j) a0 += p[(size_t)srcsorted[j] * HID + c];
    float acc = (a0 + a1) + (a2 + a3);
    float v = dis[n] * acc + b[c];
    out[(size_t)n * HID + c] = RELU ? fmaxf(v, 0.f) : v;
}

// --- p2 = (out1 @ W2) * dis[n]  (64 -> 64), LDS-tiled block GEMM -----------
#define G2_NODES 64
__global__ __launch_bounds__(256) void gemm2_kernel(const float* __restrict__ h,
                                                    const float* __restrict__ W2,
                                                    const float* __restrict__ dis,
                                                    float* __restrict__ p2) {
    __shared__ float w[HID * HID];
    __shared__ float ht[G2_NODES][HID + 1];
    int tid = threadIdx.x;
    for (int i = tid * 4; i < HID * HID; i += 256 * 4)
        *(float4*)&w[i] = *(const float4*)&W2[i];
    int n0 = blockIdx.x * G2_NODES;
    for (int i = tid; i < G2_NODES * HID / 4; i += 256) {
        int r = (i * 4) >> 6;
        int cc = (i * 4) & 63;
        float4 v = make_float4(0.f, 0.f, 0.f, 0.f);
        if (n0 + r < N_NODES) v = *(const float4*)&h[(size_t)(n0 + r) * HID + cc];
        ht[r][cc] = v.x; ht[r][cc + 1] = v.y; ht[r][cc + 2] = v.z; ht[r][cc + 3] = v.w;
    }
    __syncthreads();
    int c4 = (tid & 15) * 4;
    int nb = (tid >> 4) * 4;
    float acc[4][4];
#pragma unroll
    for (int i = 0; i < 4; ++i)
#pragma unroll
        for (int j = 0; j < 4; ++j) acc[i][j] = 0.f;
#pragma unroll 8
    for (int k = 0; k < HID; ++k) {
        float4 wv = *(float4*)&w[k * HID + c4];
        float h0 = ht[nb + 0][k];
        float h1 = ht[nb + 1][k];
        float h2 = ht[nb + 2][k];
        float h3 = ht[nb + 3][k];
        acc[0][0] += h0 * wv.x; acc[0][1] += h0 * wv.y; acc[0][2] += h0 * wv.z; acc[0][3] += h0 * wv.w;
        acc[1][0] += h1 * wv.x; acc[1][1] += h1 * wv.y; acc[1][2] += h1 * wv.z; acc[1][3] += h1 * wv.w;
        acc[2][0] += h2 * wv.x; acc[2][1] += h2 * wv.y; acc[2][2] += h2 * wv.z; acc[2][3] += h2 * wv.w;
        acc[3][0] += h3 * wv.x; acc[3][1] += h3 * wv.y; acc[3][2] += h3 * wv.z; acc[3][3] += h3 * wv.w;
    }
#pragma unroll
    for (int i = 0; i < 4; ++i) {
        int n = n0 + nb + i;
        if (n < N_NODES) {
            float ds = dis[n];
            float4 o = make_float4(acc[i][0] * ds, acc[i][1] * ds, acc[i][2] * ds, acc[i][3] * ds);
            *(float4*)&p2[(size_t)n * HID + c4] = o;
        }
    }
}

// --- column sum of h2 [N, 64] -> gsum[64] ----------------------------------
__global__ void colsum_kernel(const float* __restrict__ h2, float* __restrict__ gsum) {
    __shared__ float red[256];
    int tid = threadIdx.x;
    int lane = tid & 63;
    int w = tid >> 6;  // 4 waves per block
    float sum = 0.f;
    for (int n = blockIdx.x * 4 + w; n < N_NODES; n += gridDim.x * 4)
        sum += h2[(size_t)n * HID + lane];
    red[tid] = sum;
    __syncthreads();
    if (tid < 64)
        atomicAdd(&gsum[tid], red[tid] + red[tid + 64] + red[tid + 128] + red[tid + 192]);
}

// --- final: sigmoid(mean(h2) @ Wfc + bfc) ----------------------------------
__global__ void final_kernel(const float* __restrict__ gsum, const float* __restrict__ Wfc,
                             const float* __restrict__ bfc, float* __restrict__ out) {
    int t = threadIdx.x;
    float v = gsum[t] * (1.0f / N_NODES) * Wfc[t];
    for (int off = 32; off > 0; off >>= 1) v += __shfl_down(v, off, 64);
    if (t == 0) out[0] = 1.0f / (1.0f + expf(-(v + bfc[0])));
}

extern "C" void kernel_launch(void* const* d_in, const int* in_sizes, int n_in,
                              void* d_out, int out_size, void* d_ws, size_t ws_size,
                              hipStream_t stream) {
    const float* x   = (const float*)d_in[0];
    const int*   ei  = (const int*)d_in[1];   // (2, E) row-major int32
    const float* W1  = (const float*)d_in[2];
    const float* b1  = (const float*)d_in[3];
    const float* W2  = (const float*)d_in[4];
    const float* b2  = (const float*)d_in[5];
    const float* Wfc = (const float*)d_in[6];
    const float* bfc = (const float*)d_in[7];
    const int* src = ei;
    const int* dst = ei + N_EDGES;

    char* ws = (char*)d_ws;
    size_t off = 0;
    auto alloc = [&](size_t bytes) {
        char* p = ws + off;
        off += (bytes + 255) & ~(size_t)255;
        return p;
    };
    float*    bufA      = (float*)   alloc((size_t)N_NODES * HID * 4);  // p1, then p2
    float*    bufB      = (float*)   alloc((size_t)N_NODES * HID * 4);  // out1, then h2
    float*    dis       = (float*)   alloc((size_t)N_NODES * 4);
    unsigned* rec       = (unsigned*)alloc((size_t)N_EDGES * 4);
    unsigned* srcsorted = (unsigned*)alloc((size_t)N_EDGES * 4);
    int*      row_ptr   = (int*)     alloc((size_t)(N_NODES + 1) * 4);
    int*      bbc       = (int*)     alloc((size_t)ASCAN_M * 4);
    int*      bbs       = (int*)     alloc((size_t)ASCAN_M * 4);
    int*      binstart  = (int*)     alloc((size_t)(NBIN + 1) * 4);
    float*    gsum      = (float*)   alloc(64 * 4);

    hipMemsetAsync(gsum, 0, 64 * 4, stream);

    int nb = (N_NODES * HID + 255) / 256;
    int g2b = (N_NODES + G2_NODES - 1) / G2_NODES;

    binA0<<<A_BLOCKS, 256, 0, stream>>>(dst, bbc);
    binScan<<<1, 1024, 0, stream>>>(bbc, bbs, binstart);
    binA1<<<A_BLOCKS, 256, 0, stream>>>(src, dst, bbs, rec);
    binCSR<<<NBIN, 256, 0, stream>>>(rec, binstart, srcsorted, row_ptr, dis);
    gemm1_kernel<<<nb, 256, 0, stream>>>(x, W1, dis, bufA);
    agg_kernel<true><<<nb, 256, 0, stream>>>(bufA, row_ptr, srcsorted, dis, b1, bufB);
    gemm2_kernel<<<g2b, 256, 0, stream>>>(bufB, W2, dis, bufA);
    agg_kernel<false><<<nb, 256, 0, stream>>>(bufA, row_ptr, srcsorted, dis, b2, bufB);
    colsum_kernel<<<512, 256, 0, stream>>>(bufB, gsum);
    final_kernel<<<1, 64, 0, stream>>>(gsum, Wfc, bfc, (float*)d_out);
}

// Round 7
// 281.237 us; speedup vs baseline: 4.9262x; 1.2373x over previous
//
#include <hip/hip_runtime.h>
#include <math.h>

#define N_NODES 100000
#define N_EDGES 1250000
#define IN_DIM 6
#define HID 64

#define BIN_SHIFT 10
#define BIN_NODES 1024
#define NBIN 98                      // ceil(100000/1024)
#define A_BLOCKS 500
#define EPB (N_EDGES / A_BLOCKS)     // 2500 exactly
#define VBLK (A_BLOCKS * 4)          // per-wave virtual blocks = 2000
#define ASCAN_M (NBIN * VBLK)        // 196000
#define SNB ((ASCAN_M + 255) / 256)  // 766

// bf16 <-> f32 helpers (RNE)
__device__ inline float bf2f(unsigned short u) { return __uint_as_float((unsigned)u << 16); }
__device__ inline unsigned short f2bf(float f) {
    unsigned u = __float_as_uint(f);
    u += 0x7FFFu + ((u >> 16) & 1u);
    return (unsigned short)(u >> 16);
}

// --- A0: per-WAVE bin histogram -> bbc[bin][vblk] --------------------------
__global__ __launch_bounds__(256) void binA0(const int* __restrict__ dst, int* __restrict__ bbc) {
    __shared__ int cnt[4 * NBIN];
    int t = threadIdx.x, w = t >> 6;
    for (int i = t; i < 4 * NBIN; i += 256) cnt[i] = 0;
    __syncthreads();
    int base = blockIdx.x * EPB;
    for (int i = t; i < EPB; i += 256)
        atomicAdd(&cnt[w * NBIN + (dst[base + i] >> BIN_SHIFT)], 1);
    __syncthreads();
    for (int i = t; i < 4 * NBIN; i += 256) {
        int ww = i / NBIN, bin = i - ww * NBIN;
        bbc[bin * VBLK + blockIdx.x * 4 + ww] = cnt[i];
    }
}

// --- scan phase 1: per-block sums of bbc -----------------------------------
__global__ __launch_bounds__(256) void scanP1(const int* __restrict__ bbc, int* __restrict__ bsum) {
    __shared__ int red[256];
    int t = threadIdx.x;
    int i = blockIdx.x * 256 + t;
    red[t] = (i < ASCAN_M) ? bbc[i] : 0;
    __syncthreads();
    for (int off = 128; off > 0; off >>= 1) {
        if (t < off) red[t] += red[t + off];
        __syncthreads();
    }
    if (t == 0) bsum[blockIdx.x] = red[0];
}

// --- scan phase 2: single block scans SNB sums -> exclusive offsets --------
__global__ __launch_bounds__(1024) void scanP2(const int* __restrict__ bsum, int* __restrict__ boff) {
    __shared__ int s[1024];
    int t = threadIdx.x;
    s[t] = (t < SNB) ? bsum[t] : 0;
    __syncthreads();
    for (int off = 1; off < 1024; off <<= 1) {
        int add = (t >= off) ? s[t - off] : 0;
        __syncthreads();
        s[t] += add;
        __syncthreads();
    }
    if (t < SNB) boff[t] = (t == 0) ? 0 : s[t - 1];
}

// --- scan phase 3: per-block scan + offset -> bbs, binstart ----------------
__global__ __launch_bounds__(256) void scanP3(const int* __restrict__ bbc, const int* __restrict__ boff,
                                              int* __restrict__ bbs, int* __restrict__ binstart) {
    __shared__ int s[256];
    int t = threadIdx.x;
    int i = blockIdx.x * 256 + t;
    int c = (i < ASCAN_M) ? bbc[i] : 0;
    s[t] = c;
    __syncthreads();
    for (int off = 1; off < 256; off <<= 1) {
        int add = (t >= off) ? s[t - off] : 0;
        __syncthreads();
        s[t] += add;
        __syncthreads();
    }
    int val = boff[blockIdx.x] + s[t] - c;
    if (i < ASCAN_M) {
        bbs[i] = val;
        if (i % VBLK == 0) binstart[i / VBLK] = val;
    }
    if (i == 0) binstart[NBIN] = N_EDGES;
}

// --- A1: records into per-WAVE private regions (no global atomics) ---------
__global__ __launch_bounds__(256) void binA1(const int* __restrict__ src, const int* __restrict__ dst,
                                             const int* __restrict__ bbs, unsigned* __restrict__ rec) {
    __shared__ int cur[4 * NBIN];
    int t = threadIdx.x, w = t >> 6;
    for (int i = t; i < 4 * NBIN; i += 256) {
        int ww = i / NBIN, bin = i - ww * NBIN;
        cur[i] = bbs[bin * VBLK + blockIdx.x * 4 + ww];
    }
    __syncthreads();
    int base = blockIdx.x * EPB;
    for (int i = t; i < EPB; i += 256) {
        int d = dst[base + i];
        int s = src[base + i];
        int bin = d >> BIN_SHIFT;
        int pos = atomicAdd(&cur[w * NBIN + bin], 1);
        rec[pos] = ((unsigned)(d & (BIN_NODES - 1)) << 17) | (unsigned)s;
    }
}

// --- per-bin CSR-ify: node hist -> scan -> dst-sorted src, row_ptr, dis ----
__global__ __launch_bounds__(512) void binCSR(const unsigned* __restrict__ rec,
                                              const int* __restrict__ binstart,
                                              unsigned* __restrict__ srcsorted,
                                              int* __restrict__ row_ptr, float* __restrict__ dis) {
    __shared__ int hist[BIN_NODES];
    __shared__ int sc[512];
    int t = threadIdx.x;
    int bin = blockIdx.x;
    for (int i = t; i < BIN_NODES; i += 512) hist[i] = 0;
    __syncthreads();
    int beg = binstart[bin], end = binstart[bin + 1];
    for (int j = beg + t; j < end; j += 512) atomicAdd(&hist[rec[j] >> 17], 1);
    __syncthreads();
    int c0 = hist[2 * t], c1 = hist[2 * t + 1];
    int tsum = c0 + c1;
    sc[t] = tsum;
    __syncthreads();
    for (int off = 1; off < 512; off <<= 1) {
        int add = (t >= off) ? sc[t - off] : 0;
        __syncthreads();
        sc[t] += add;
        __syncthreads();
    }
    int o0 = sc[t] - tsum;
    int o1 = o0 + c0;
    int n0 = (bin << BIN_SHIFT) + 2 * t;
    if (n0 + 0 < N_NODES) { row_ptr[n0 + 0] = beg + o0; dis[n0 + 0] = rsqrtf((float)c0 + 1.0f); }
    if (n0 + 1 < N_NODES) { row_ptr[n0 + 1] = beg + o1; dis[n0 + 1] = rsqrtf((float)c1 + 1.0f); }
    if (bin == NBIN - 1 && t == 0) row_ptr[N_NODES] = N_EDGES;
    __syncthreads();
    hist[2 * t] = o0; hist[2 * t + 1] = o1;
    __syncthreads();
    for (int j = beg + t; j < end; j += 512) {
        unsigned r = rec[j];
        int pos = atomicAdd(&hist[r >> 17], 1);
        srcsorted[beg + pos] = r & 131071u;
    }
}

// --- p1 = bf16((x @ W1) * dis[n])  (6 -> 64) -------------------------------
__global__ void gemm1_kernel(const float* __restrict__ x, const float* __restrict__ W1,
                             const float* __restrict__ dis, unsigned short* __restrict__ p1) {
    __shared__ float w[IN_DIM * HID];
    int tid = threadIdx.x;
    for (int i = tid; i < IN_DIM * HID; i += blockDim.x) w[i] = W1[i];
    __syncthreads();
    int g = blockIdx.x * blockDim.x + tid;
    int n = g >> 6, c = g & 63;
    if (n >= N_NODES) return;
    float sum = 0.f;
#pragma unroll
    for (int k = 0; k < IN_DIM; ++k) sum += x[n * IN_DIM + k] * w[k * HID + c];
    p1[(size_t)n * HID + c] = f2bf(sum * dis[n]);
}

// --- aggregation: out[n] = bf16(act(dis[n]*(p[n] + sum_in p[src]) + b)) ----
// One wave per node, lane = channel, bf16 rows (128 B), x8 unrolled gather.
template <bool RELU>
__global__ __launch_bounds__(256) void agg_kernel(const unsigned short* __restrict__ p,
                                                  const int* __restrict__ row_ptr,
                                                  const unsigned* __restrict__ srcsorted,
                                                  const float* __restrict__ dis,
                                                  const float* __restrict__ b,
                                                  unsigned short* __restrict__ out) {
    int g = blockIdx.x * blockDim.x + threadIdx.x;
    int n = g >> 6, c = g & 63;
    if (n >= N_NODES) return;
    int beg = row_ptr[n], end = row_ptr[n + 1];
    float a0 = bf2f(p[(size_t)n * HID + c]), a1 = 0.f, a2 = 0.f, a3 = 0.f;
    int j = beg;
    for (; j + 8 <= end; j += 8) {
        unsigned s0 = srcsorted[j + 0], s1 = srcsorted[j + 1];
        unsigned s2 = srcsorted[j + 2], s3 = srcsorted[j + 3];
        unsigned s4 = srcsorted[j + 4], s5 = srcsorted[j + 5];
        unsigned s6 = srcsorted[j + 6], s7 = srcsorted[j + 7];
        unsigned short v0 = p[(size_t)s0 * HID + c];
        unsigned short v1 = p[(size_t)s1 * HID + c];
        unsigned short v2 = p[(size_t)s2 * HID + c];
        unsigned short v3 = p[(size_t)s3 * HID + c];
        unsigned short v4 = p[(size_t)s4 * HID + c];
        unsigned short v5 = p[(size_t)s5 * HID + c];
        unsigned short v6 = p[(size_t)s6 * HID + c];
        unsigned short v7 = p[(size_t)s7 * HID + c];
        a0 += bf2f(v0) + bf2f(v4);
        a1 += bf2f(v1) + bf2f(v5);
        a2 += bf2f(v2) + bf2f(v6);
        a3 += bf2f(v3) + bf2f(v7);
    }
    for (; j + 2 <= end; j += 2) {
        unsigned s0 = srcsorted[j], s1 = srcsorted[j + 1];
        a0 += bf2f(p[(size_t)s0 * HID + c]);
        a1 += bf2f(p[(size_t)s1 * HID + c]);
    }
    if (j < end) a2 += bf2f(p[(size_t)srcsorted[j] * HID + c]);
    float v = dis[n] * ((a0 + a1) + (a2 + a3)) + b[c];
    out[(size_t)n * HID + c] = f2bf(RELU ? fmaxf(v, 0.f) : v);
}

// --- p2 = bf16((h1 @ W2) * dis[n])  (64 -> 64), LDS-tiled ------------------
#define G2_NODES 64
__global__ __launch_bounds__(256) void gemm2_kernel(const unsigned short* __restrict__ h,
                                                    const float* __restrict__ W2,
                                                    const float* __restrict__ dis,
                                                    unsigned short* __restrict__ p2) {
    __shared__ float w[HID * HID];
    __shared__ float ht[G2_NODES][HID + 1];
    int tid = threadIdx.x;
    for (int i = tid * 4; i < HID * HID; i += 256 * 4)
        *(float4*)&w[i] = *(const float4*)&W2[i];
    int n0 = blockIdx.x * G2_NODES;
    for (int i = tid; i < G2_NODES * HID / 4; i += 256) {
        int r = (i * 4) >> 6;
        int cc = (i * 4) & 63;
        float f0 = 0.f, f1 = 0.f, f2 = 0.f, f3 = 0.f;
        if (n0 + r < N_NODES) {
            uint2 raw = *(const uint2*)&h[(size_t)(n0 + r) * HID + cc];
            f0 = bf2f((unsigned short)(raw.x & 0xffffu));
            f1 = bf2f((unsigned short)(raw.x >> 16));
            f2 = bf2f((unsigned short)(raw.y & 0xffffu));
            f3 = bf2f((unsigned short)(raw.y >> 16));
        }
        ht[r][cc] = f0; ht[r][cc + 1] = f1; ht[r][cc + 2] = f2; ht[r][cc + 3] = f3;
    }
    __syncthreads();
    int c4 = (tid & 15) * 4;
    int nb = (tid >> 4) * 4;
    float acc[4][4];
#pragma unroll
    for (int i = 0; i < 4; ++i)
#pragma unroll
        for (int j = 0; j < 4; ++j) acc[i][j] = 0.f;
#pragma unroll 8
    for (int k = 0; k < HID; ++k) {
        float4 wv = *(float4*)&w[k * HID + c4];
        float h0 = ht[nb + 0][k];
        float h1 = ht[nb + 1][k];
        float h2 = ht[nb + 2][k];
        float h3 = ht[nb + 3][k];
        acc[0][0] += h0 * wv.x; acc[0][1] += h0 * wv.y; acc[0][2] += h0 * wv.z; acc[0][3] += h0 * wv.w;
        acc[1][0] += h1 * wv.x; acc[1][1] += h1 * wv.y; acc[1][2] += h1 * wv.z; acc[1][3] += h1 * wv.w;
        acc[2][0] += h2 * wv.x; acc[2][1] += h2 * wv.y; acc[2][2] += h2 * wv.z; acc[2][3] += h2 * wv.w;
        acc[3][0] += h3 * wv.x; acc[3][1] += h3 * wv.y; acc[3][2] += h3 * wv.z; acc[3][3] += h3 * wv.w;
    }
#pragma unroll
    for (int i = 0; i < 4; ++i) {
        int n = n0 + nb + i;
        if (n < N_NODES) {
            float ds = dis[n];
            uint2 pk;
            pk.x = (unsigned)f2bf(acc[i][0] * ds) | ((unsigned)f2bf(acc[i][1] * ds) << 16);
            pk.y = (unsigned)f2bf(acc[i][2] * ds) | ((unsigned)f2bf(acc[i][3] * ds) << 16);
            *(uint2*)&p2[(size_t)n * HID + c4] = pk;
        }
    }
}

// --- column sum of bf16 h2 [N, 64] -> gsum[64] -----------------------------
__global__ void colsum_kernel(const unsigned short* __restrict__ h2, float* __restrict__ gsum) {
    __shared__ float red[256];
    int tid = threadIdx.x;
    int lane = tid & 63;
    int w = tid >> 6;  // 4 waves per block
    float sum = 0.f;
    for (int n = blockIdx.x * 4 + w; n < N_NODES; n += gridDim.x * 4)
        sum += bf2f(h2[(size_t)n * HID + lane]);
    red[tid] = sum;
    __syncthreads();
    if (tid < 64)
        atomicAdd(&gsum[tid], red[tid] + red[tid + 64] + red[tid + 128] + red[tid + 192]);
}

// --- final: sigmoid(mean(h2) @ Wfc + bfc) ----------------------------------
__global__ void final_kernel(const float* __restrict__ gsum, const float* __restrict__ Wfc,
                             const float* __restrict__ bfc, float* __restrict__ out) {
    int t = threadIdx.x;
    float v = gsum[t] * (1.0f / N_NODES) * Wfc[t];
    for (int off = 32; off > 0; off >>= 1) v += __shfl_down(v, off, 64);
    if (t == 0) out[0] = 1.0f / (1.0f + expf(-(v + bfc[0])));
}

extern "C" void kernel_launch(void* const* d_in, const int* in_sizes, int n_in,
                              void* d_out, int out_size, void* d_ws, size_t ws_size,
                              hipStream_t stream) {
    const float* x   = (const float*)d_in[0];
    const int*   ei  = (const int*)d_in[1];   // (2, E) row-major int32
    const float* W1  = (const float*)d_in[2];
    const float* b1  = (const float*)d_in[3];
    const float* W2  = (const float*)d_in[4];
    const float* b2  = (const float*)d_in[5];
    const float* Wfc = (const float*)d_in[6];
    const float* bfc = (const float*)d_in[7];
    const int* src = ei;
    const int* dst = ei + N_EDGES;

    char* ws = (char*)d_ws;
    size_t off = 0;
    auto alloc = [&](size_t bytes) {
        char* p = ws + off;
        off += (bytes + 255) & ~(size_t)255;
        return p;
    };
    unsigned short* bufA     = (unsigned short*)alloc((size_t)N_NODES * HID * 2);  // p1, then p2
    unsigned short* bufB     = (unsigned short*)alloc((size_t)N_NODES * HID * 2);  // h1, then h2
    float*          dis      = (float*)   alloc((size_t)N_NODES * 4);
    unsigned*       rec      = (unsigned*)alloc((size_t)N_EDGES * 4);
    unsigned*       srcsorted= (unsigned*)alloc((size_t)N_EDGES * 4);
    int*            row_ptr  = (int*)     alloc((size_t)(N_NODES + 1) * 4);
    int*            bbc      = (int*)     alloc((size_t)ASCAN_M * 4);
    int*            bbs      = (int*)     alloc((size_t)ASCAN_M * 4);
    int*            bsum     = (int*)     alloc((size_t)SNB * 4);
    int*            boff     = (int*)     alloc((size_t)SNB * 4);
    int*            binstart = (int*)     alloc((size_t)(NBIN + 1) * 4);
    float*          gsum     = (float*)   alloc(64 * 4);

    hipMemsetAsync(gsum, 0, 64 * 4, stream);

    int nb = (N_NODES * HID + 255) / 256;  // 25000
    int g2b = (N_NODES + G2_NODES - 1) / G2_NODES;

    binA0<<<A_BLOCKS, 256, 0, stream>>>(dst, bbc);
    scanP1<<<SNB, 256, 0, stream>>>(bbc, bsum);
    scanP2<<<1, 1024, 0, stream>>>(bsum, boff);
    scanP3<<<SNB, 256, 0, stream>>>(bbc, boff, bbs, binstart);
    binA1<<<A_BLOCKS, 256, 0, stream>>>(src, dst, bbs, rec);
    binCSR<<<NBIN, 512, 0, stream>>>(rec, binstart, srcsorted, row_ptr, dis);
    gemm1_kernel<<<nb, 256, 0, stream>>>(x, W1, dis, bufA);
    agg_kernel<true><<<nb, 256, 0, stream>>>(bufA, row_ptr, srcsorted, dis, b1, bufB);
    gemm2_kernel<<<g2b, 256, 0, stream>>>(bufB, W2, dis, bufA);
    agg_kernel<false><<<nb, 256, 0, stream>>>(bufA, row_ptr, srcsorted, dis, b2, bufB);
    colsum_kernel<<<512, 256, 0, stream>>>(bufB, gsum);
    final_kernel<<<1, 64, 0, stream>>>(gsum, Wfc, bfc, (float*)d_out);
}